// Round 3
// baseline (1665.101 us; speedup 1.0000x reference)
//
#include <hip/hip_runtime.h>

typedef __bf16 bf16;
typedef __attribute__((ext_vector_type(8))) __bf16 bf16x8;
typedef __attribute__((ext_vector_type(4))) float f32x4;

#define MFMA_BF16(a,b,c) __builtin_amdgcn_mfma_f32_16x16x32_bf16((a),(b),(c),0,0,0)

__device__ __forceinline__ void gld_lds16(const void* g, void* l) {
  __builtin_amdgcn_global_load_lds(
      (__attribute__((address_space(1))) void*)(g),
      (__attribute__((address_space(3))) void*)(l), 16, 0, 0);
}

__device__ __forceinline__ bf16x8 cvt8(float4 u, float4 v) {
  bf16x8 r;
  r[0] = (bf16)u.x; r[1] = (bf16)u.y; r[2] = (bf16)u.z; r[3] = (bf16)u.w;
  r[4] = (bf16)v.x; r[5] = (bf16)v.y; r[6] = (bf16)v.z; r[7] = (bf16)v.w;
  return r;
}

__global__ __launch_bounds__(256) void fill_kernel(float* p, int n, float v) {
  int i = blockIdx.x * 256 + threadIdx.x;
  if (i < n) p[i] = v;
}

// C[m][n] = sum_k A[m][k] * W[n][k]; A,W fp32 row-major 4096x4096, staged->bf16.
// z==2 writes C transposed as VT layout (b,h,d,s); else bf16 row-major.
__global__ __launch_bounds__(256) void gemm_f32in(
    const float* __restrict__ A,
    const float* __restrict__ W0, const float* __restrict__ W1, const float* __restrict__ W2,
    bf16* __restrict__ C0, bf16* __restrict__ C1, bf16* __restrict__ C2)
{
  constexpr int K = 4096, N = 4096;
  __shared__ __align__(16) bf16 As[128 * 32];
  __shared__ __align__(16) bf16 Bs[128 * 32];
  const int z = blockIdx.z;
  const float* __restrict__ W = (z == 0) ? W0 : ((z == 1) ? W1 : W2);
  bf16* __restrict__ C = (z == 0) ? C0 : ((z == 1) ? C1 : C2);
  const int tid = threadIdx.x;
  const int lane = tid & 63, wave = tid >> 6;
  const int l15 = lane & 15, quad = lane >> 4;
  const int m0 = blockIdx.x * 128, n0 = blockIdx.y * 128;
  const int wm = (wave & 1) * 64, wn = (wave >> 1) * 64;

  const int srow = tid >> 2;          // 0..63
  const int scol = (tid & 3) * 8;     // 0,8,16,24
  const float* gA = A + (size_t)(m0 + srow) * K + scol;
  const float* gW = W + (size_t)(n0 + srow) * K + scol;
  bf16* lA = &As[srow * 32 + scol];
  bf16* lB = &Bs[srow * 32 + scol];

  f32x4 acc[4][4];
#pragma unroll
  for (int i = 0; i < 4; i++)
#pragma unroll
    for (int j = 0; j < 4; j++) acc[i][j] = (f32x4){0.f, 0.f, 0.f, 0.f};

  for (int k0 = 0; k0 < K; k0 += 32) {
    float4 a0 = *(const float4*)(gA + k0);
    float4 a1 = *(const float4*)(gA + k0 + 4);
    float4 a2 = *(const float4*)(gA + k0 + (size_t)64 * K);
    float4 a3 = *(const float4*)(gA + k0 + (size_t)64 * K + 4);
    float4 b0 = *(const float4*)(gW + k0);
    float4 b1 = *(const float4*)(gW + k0 + 4);
    float4 b2 = *(const float4*)(gW + k0 + (size_t)64 * K);
    float4 b3 = *(const float4*)(gW + k0 + (size_t)64 * K + 4);
    __syncthreads();   // previous iteration's LDS reads complete
    *(bf16x8*)lA              = cvt8(a0, a1);
    *(bf16x8*)(lA + 64 * 32)  = cvt8(a2, a3);
    *(bf16x8*)lB              = cvt8(b0, b1);
    *(bf16x8*)(lB + 64 * 32)  = cvt8(b2, b3);
    __syncthreads();
    bf16x8 af[4], bfr[4];
#pragma unroll
    for (int i = 0; i < 4; i++) af[i]  = *(const bf16x8*)&As[(wm + i * 16 + l15) * 32 + quad * 8];
#pragma unroll
    for (int j = 0; j < 4; j++) bfr[j] = *(const bf16x8*)&Bs[(wn + j * 16 + l15) * 32 + quad * 8];
#pragma unroll
    for (int i = 0; i < 4; i++)
#pragma unroll
      for (int j = 0; j < 4; j++)
        acc[i][j] = MFMA_BF16(af[i], bfr[j], acc[i][j]);
  }

  if (z == 2) {
    // VT[((b*32+h)*128 + d)*2048 + s]; n=h*128+d; m=b*2048+s
#pragma unroll
    for (int i = 0; i < 4; i++) {
      const int mg = m0 + wm + i * 16 + quad * 4;
      const int bb = mg >> 11, ss = mg & 2047;
#pragma unroll
      for (int j = 0; j < 4; j++) {
        const int n = n0 + wn + j * 16 + l15;
        ushort4 pk;
        pk.x = __builtin_bit_cast(unsigned short, (bf16)acc[i][j][0]);
        pk.y = __builtin_bit_cast(unsigned short, (bf16)acc[i][j][1]);
        pk.z = __builtin_bit_cast(unsigned short, (bf16)acc[i][j][2]);
        pk.w = __builtin_bit_cast(unsigned short, (bf16)acc[i][j][3]);
        *(ushort4*)&C[((size_t)bb * 4096 + n) * 2048 + ss] = pk;
      }
    }
  } else {
#pragma unroll
    for (int i = 0; i < 4; i++) {
      const int row = m0 + wm + i * 16 + quad * 4;
#pragma unroll
      for (int j = 0; j < 4; j++) {
        const int col = n0 + wn + j * 16 + l15;
#pragma unroll
        for (int r = 0; r < 4; r++)
          C[(size_t)(row + r) * N + col] = (bf16)acc[i][j][r];
      }
    }
  }
}

// Final projection: C(fp32) = A(bf16) @ W(fp32)^T
__global__ __launch_bounds__(256) void gemm_out(
    const bf16* __restrict__ A, const float* __restrict__ W, float* __restrict__ C)
{
  constexpr int K = 4096, N = 4096;
  __shared__ __align__(16) bf16 As[128 * 32];
  __shared__ __align__(16) bf16 Bs[128 * 32];
  const int tid = threadIdx.x;
  const int lane = tid & 63, wave = tid >> 6;
  const int l15 = lane & 15, quad = lane >> 4;
  const int m0 = blockIdx.x * 128, n0 = blockIdx.y * 128;
  const int wm = (wave & 1) * 64, wn = (wave >> 1) * 64;

  const int srow = tid >> 2;
  const int scol = (tid & 3) * 8;
  const bf16* gA  = A + (size_t)(m0 + srow) * K + scol;
  const float* gW = W + (size_t)(n0 + srow) * K + scol;
  bf16* lA = &As[srow * 32 + scol];
  bf16* lB = &Bs[srow * 32 + scol];

  f32x4 acc[4][4];
#pragma unroll
  for (int i = 0; i < 4; i++)
#pragma unroll
    for (int j = 0; j < 4; j++) acc[i][j] = (f32x4){0.f, 0.f, 0.f, 0.f};

  for (int k0 = 0; k0 < K; k0 += 32) {
    float4 b0 = *(const float4*)(gW + k0);
    float4 b1 = *(const float4*)(gW + k0 + 4);
    float4 b2 = *(const float4*)(gW + k0 + (size_t)64 * K);
    float4 b3 = *(const float4*)(gW + k0 + (size_t)64 * K + 4);
    __syncthreads();
    gld_lds16(gA + k0,                 lA);
    gld_lds16(gA + k0 + (size_t)64 * K, lA + 64 * 32);
    *(bf16x8*)lB             = cvt8(b0, b1);
    *(bf16x8*)(lB + 64 * 32) = cvt8(b2, b3);
    __syncthreads();
    bf16x8 af[4], bfr[4];
#pragma unroll
    for (int i = 0; i < 4; i++) af[i]  = *(const bf16x8*)&As[(wm + i * 16 + l15) * 32 + quad * 8];
#pragma unroll
    for (int j = 0; j < 4; j++) bfr[j] = *(const bf16x8*)&Bs[(wn + j * 16 + l15) * 32 + quad * 8];
#pragma unroll
    for (int i = 0; i < 4; i++)
#pragma unroll
      for (int j = 0; j < 4; j++)
        acc[i][j] = MFMA_BF16(af[i], bfr[j], acc[i][j]);
  }

#pragma unroll
  for (int i = 0; i < 4; i++) {
    const int row = m0 + wm + i * 16 + quad * 4;
#pragma unroll
    for (int j = 0; j < 4; j++) {
      const int col = n0 + wn + j * 16 + l15;
#pragma unroll
      for (int r = 0; r < 4; r++)
        C[(size_t)(row + r) * N + col] = acc[i][j][r];
    }
  }
}

// Interleaved RoPE on q and k (bf16) in-place; freqs are fp32.
__global__ __launch_bounds__(256) void rope_kernel(
    bf16* __restrict__ q, bf16* __restrict__ kk,
    const float* __restrict__ fc, const float* __restrict__ fs)
{
  const int t = blockIdx.x * 256 + threadIdx.x;   // 0 .. 2097151
  const int i4 = (t & 15) << 2;                   // pair base 0..60
  const int row = t >> 4;                         // (b*2048+s)*32 + h
  const int s = (row >> 5) & 2047;

  float4 c4 = *(const float4*)(fc + s * 64 + i4);
  float4 s4 = *(const float4*)(fs + s * 64 + i4);
  float c[4]  = {c4.x, c4.y, c4.z, c4.w};
  float sn[4] = {s4.x, s4.y, s4.z, s4.w};

  const int off = row * 128 + (i4 << 1);
  uint4 qv = *(const uint4*)(q + off);
  uint4 kv = *(const uint4*)(kk + off);
  unsigned qa[4] = {qv.x, qv.y, qv.z, qv.w};
  unsigned ka[4] = {kv.x, kv.y, kv.z, kv.w};
#pragma unroll
  for (int p = 0; p < 4; p++) {
    float x0 = __builtin_bit_cast(float, (qa[p] & 0xffffu) << 16);
    float x1 = __builtin_bit_cast(float, (qa[p] >> 16) << 16);
    unsigned lo = __builtin_bit_cast(unsigned short, (bf16)(x0 * c[p] - x1 * sn[p]));
    unsigned hi = __builtin_bit_cast(unsigned short, (bf16)(x0 * sn[p] + x1 * c[p]));
    qa[p] = lo | (hi << 16);
    float y0 = __builtin_bit_cast(float, (ka[p] & 0xffffu) << 16);
    float y1 = __builtin_bit_cast(float, (ka[p] >> 16) << 16);
    lo = __builtin_bit_cast(unsigned short, (bf16)(y0 * c[p] - y1 * sn[p]));
    hi = __builtin_bit_cast(unsigned short, (bf16)(y0 * sn[p] + y1 * c[p]));
    ka[p] = lo | (hi << 16);
  }
  *(uint4*)(q + off)  = make_uint4(qa[0], qa[1], qa[2], qa[3]);
  *(uint4*)(kk + off) = make_uint4(ka[0], ka[1], ka[2], ka[3]);
}

// Flash attention, causal. Block = (64 q-rows, head h, batch b); 4 waves x 16-row strips.
// All operands bf16 in workspace. O written over the block's own Q slice.
__global__ __launch_bounds__(256) void flash_attn(
    const bf16* __restrict__ Kg_, const bf16* __restrict__ VT, bf16* __restrict__ QO)
{
  __shared__ __align__(16) bf16 Qs[64 * 128];  // reused as P after Q-frags load
  __shared__ __align__(16) bf16 Ks[64 * 128];
  __shared__ __align__(16) bf16 Vs[128 * 64];

  const int tid = threadIdx.x, lane = tid & 63, wave = tid >> 6;
  const int l15 = lane & 15, quad = lane >> 4;
  const int q0 = blockIdx.x * 64, h = blockIdx.y, b = blockIdx.z;

  bf16* Qg       = QO  + ((size_t)(b * 2048 + q0) * 32 + h) * 128;   // row stride 4096
  const bf16* Kg = Kg_ + ((size_t)b * 2048 * 32 + h) * 128;
  const bf16* Vg = VT  + ((size_t)(b * 32 + h)) * 128 * 2048;        // row(d) stride 2048

#pragma unroll
  for (int it = 0; it < 4; ++it) {
    int c = it * 256 + tid;
    gld_lds16(Qg + (size_t)(c >> 4) * 4096 + (c & 15) * 8, &Qs[c * 8]);
  }
  __syncthreads();
  bf16x8 qf[4];
#pragma unroll
  for (int ks = 0; ks < 4; ks++)
    qf[ks] = *(const bf16x8*)&Qs[(wave * 16 + l15) * 128 + ks * 32 + quad * 8];

  bf16* Ps = &Qs[wave * (16 * 72)];   // per-wave P buffer, padded stride 72

  float m_i[4], l_i[4];
  f32x4 oacc[8];
#pragma unroll
  for (int r = 0; r < 4; r++) { m_i[r] = -INFINITY; l_i[r] = 0.f; }
#pragma unroll
  for (int j = 0; j < 8; j++) oacc[j] = (f32x4){0.f, 0.f, 0.f, 0.f};

  const float SCL = 0.08838834764831845f * 1.4426950408889634f;  // 1/sqrt(128)*log2(e)

  const int nkt = blockIdx.x + 1;
  for (int kt = 0; kt < nkt; ++kt) {
    __syncthreads();
    const bf16* Kt = Kg + (size_t)kt * 64 * 4096;
    const bf16* Vt = Vg + kt * 64;
#pragma unroll
    for (int it = 0; it < 4; ++it) {
      int c = it * 256 + tid;
      gld_lds16(Kt + (size_t)(c >> 4) * 4096 + (c & 15) * 8, &Ks[c * 8]);
      gld_lds16(Vt + (size_t)(c >> 3) * 2048 + (c & 7) * 8, &Vs[c * 8]);
    }
    __syncthreads();

    f32x4 sacc[4];
#pragma unroll
    for (int nb = 0; nb < 4; nb++) {
      f32x4 a = (f32x4){0.f, 0.f, 0.f, 0.f};
#pragma unroll
      for (int ks = 0; ks < 4; ks++) {
        bf16x8 kf = *(const bf16x8*)&Ks[(nb * 16 + l15) * 128 + ks * 32 + quad * 8];
        a = MFMA_BF16(qf[ks], kf, a);
      }
      sacc[nb] = a;
    }

    const int qb = q0 + wave * 16 + quad * 4;
    const int kb = kt * 64 + l15;
    float alpha[4];
#pragma unroll
    for (int r = 0; r < 4; r++) {
      float mx = -INFINITY;
#pragma unroll
      for (int nb = 0; nb < 4; nb++) {
        float s = sacc[nb][r] * SCL;
        if (kb + nb * 16 > qb + r) s = -INFINITY;   // causal mask
        sacc[nb][r] = s;
        mx = fmaxf(mx, s);
      }
#pragma unroll
      for (int off = 1; off < 16; off <<= 1) mx = fmaxf(mx, __shfl_xor(mx, off));
      float mn = fmaxf(m_i[r], mx);
      alpha[r] = exp2f(m_i[r] - mn);
      m_i[r] = mn;
      float rs = 0.f;
#pragma unroll
      for (int nb = 0; nb < 4; nb++) {
        float p = exp2f(sacc[nb][r] - mn);
        rs += p;
        Ps[(quad * 4 + r) * 72 + nb * 16 + l15] = (bf16)p;
      }
#pragma unroll
      for (int off = 1; off < 16; off <<= 1) rs += __shfl_xor(rs, off);
      l_i[r] = l_i[r] * alpha[r] + rs;
    }
#pragma unroll
    for (int j = 0; j < 8; j++)
#pragma unroll
      for (int r = 0; r < 4; r++) oacc[j][r] *= alpha[r];

    __syncthreads();   // P visible to the wave's reads below

#pragma unroll
    for (int ks2 = 0; ks2 < 2; ks2++) {
      bf16x8 pf = *(const bf16x8*)&Ps[l15 * 72 + ks2 * 32 + quad * 8];
#pragma unroll
      for (int j = 0; j < 8; j++) {
        bf16x8 vf = *(const bf16x8*)&Vs[(j * 16 + l15) * 64 + ks2 * 32 + quad * 8];
        oacc[j] = MFMA_BF16(pf, vf, oacc[j]);
      }
    }
  }

#pragma unroll
  for (int r = 0; r < 4; r++) {
    const float inv = 1.f / l_i[r];
    const int row = q0 + wave * 16 + quad * 4 + r;
    bf16* Og = QO + ((size_t)(b * 2048 + row) * 32 + h) * 128;
#pragma unroll
    for (int j = 0; j < 8; j++) Og[j * 16 + l15] = (bf16)(oacc[j][r] * inv);
  }
}

extern "C" void kernel_launch(void* const* d_in, const int* in_sizes, int n_in,
                              void* d_out, int out_size, void* d_ws, size_t ws_size,
                              hipStream_t stream) {
  const float* x  = (const float*)d_in[0];
  const float* wq = (const float*)d_in[1];
  const float* wk = (const float*)d_in[2];
  const float* wv = (const float*)d_in[3];
  const float* wo = (const float*)d_in[4];
  const float* fc = (const float*)d_in[5];
  const float* fs = (const float*)d_in[6];
  // d_in[7] = mask (analytic), d_in[8] = start_pos (0)
  float* out = (float*)d_out;

  // Sentinels localize infra failures via absmax.
  float sentinel = 0.f;
  if (n_in < 9 || in_sizes[0] != 16777216) sentinel = 200.f;
  else if (out_size != 16777216)           sentinel = 300.f;
  else if (in_sizes[5] != 131072)          sentinel = 400.f;
  else if (ws_size < 3ull * 33554432ull)   sentinel = 100.f;  // need 96 MiB
  if (sentinel != 0.f) {
    fill_kernel<<<dim3((out_size + 255) / 256), dim3(256), 0, stream>>>(out, out_size, sentinel);
    return;
  }

  bf16* q  = (bf16*)d_ws;                    // (b,s,h,d); becomes attention output in-place
  bf16* k  = q  + (size_t)16777216;          // (b,s,h,d)
  bf16* vt = k  + (size_t)16777216;          // (b,h,d,s)

  dim3 blk(256, 1, 1);
  gemm_f32in<<<dim3(32, 32, 3), blk, 0, stream>>>(x, wq, wk, wv, q, k, vt);
  rope_kernel<<<dim3(8192, 1, 1), blk, 0, stream>>>(q, k, fc, fs);
  flash_attn<<<dim3(32, 32, 2), blk, 0, stream>>>(k, vt, q);
  gemm_out<<<dim3(32, 32, 1), blk, 0, stream>>>(q, wo, out);
}

// Round 4
// 1552.238 us; speedup vs baseline: 1.0727x; 1.0727x over previous
//
#include <hip/hip_runtime.h>

typedef __bf16 bf16;
typedef __attribute__((ext_vector_type(8))) __bf16 bf16x8;
typedef __attribute__((ext_vector_type(4))) float f32x4;

#define MFMA_BF16(a,b,c) __builtin_amdgcn_mfma_f32_16x16x32_bf16((a),(b),(c),0,0,0)

__device__ __forceinline__ void gld_lds16(const void* g, void* l) {
  __builtin_amdgcn_global_load_lds(
      (__attribute__((address_space(1))) void*)(g),
      (__attribute__((address_space(3))) void*)(l), 16, 0, 0);
}

__device__ __forceinline__ bf16x8 cvt8(float4 u, float4 v) {
  bf16x8 r;
  r[0] = (bf16)u.x; r[1] = (bf16)u.y; r[2] = (bf16)u.z; r[3] = (bf16)u.w;
  r[4] = (bf16)v.x; r[5] = (bf16)v.y; r[6] = (bf16)v.z; r[7] = (bf16)v.w;
  return r;
}

__global__ __launch_bounds__(256) void fill_kernel(float* p, int n, float v) {
  int i = blockIdx.x * 256 + threadIdx.x;
  if (i < n) p[i] = v;
}

// fp32 -> bf16, 4 elems/thread (16B coalesced loads, 8B stores)
__global__ __launch_bounds__(256) void cvt_kernel(const float* __restrict__ s, bf16* __restrict__ d) {
  size_t i = ((size_t)blockIdx.x * 256 + threadIdx.x) * 4;
  float4 a = *(const float4*)(s + i);
  ushort4 r;
  r.x = __builtin_bit_cast(unsigned short, (bf16)a.x);
  r.y = __builtin_bit_cast(unsigned short, (bf16)a.y);
  r.z = __builtin_bit_cast(unsigned short, (bf16)a.z);
  r.w = __builtin_bit_cast(unsigned short, (bf16)a.w);
  *(ushort4*)(d + i) = r;
}

// ---------------- pure-bf16 m97-style GEMM (A bf16, W bf16) ----------------
// C[m][n] = sum_k A[m][k]*W[n][k]. z==2 -> VT transposed epilogue (b,h,d,s).
__global__ __launch_bounds__(256) void gemm_bt_bf(
    const bf16* __restrict__ A,
    const bf16* __restrict__ W0, const bf16* __restrict__ W1, const bf16* __restrict__ W2,
    bf16* __restrict__ C0, bf16* __restrict__ C1, bf16* __restrict__ C2)
{
  constexpr int K = 4096, N = 4096;
  __shared__ __align__(16) bf16 As[128 * 32];
  __shared__ __align__(16) bf16 Bs[128 * 32];
  const int z = blockIdx.z;
  const bf16* __restrict__ W = (z == 0) ? W0 : ((z == 1) ? W1 : W2);
  bf16* __restrict__ C = (z == 0) ? C0 : ((z == 1) ? C1 : C2);
  const int tid = threadIdx.x;
  const int lane = tid & 63, wave = tid >> 6;
  const int l15 = lane & 15, quad = lane >> 4;
  const int m0 = blockIdx.x * 128, n0 = blockIdx.y * 128;
  const int wm = (wave & 1) * 64, wn = (wave >> 1) * 64;

  const int srow = tid >> 2;          // 0..63
  const int scol = (tid & 3) * 8;     // elems
  const bf16* gA = A + (size_t)(m0 + srow) * K + scol;
  const bf16* gW = W + (size_t)(n0 + srow) * K + scol;
  bf16* lA = &As[srow * 32 + scol];
  bf16* lB = &Bs[srow * 32 + scol];

  f32x4 acc[4][4];
#pragma unroll
  for (int i = 0; i < 4; i++)
#pragma unroll
    for (int j = 0; j < 4; j++) acc[i][j] = (f32x4){0.f, 0.f, 0.f, 0.f};

  for (int k0 = 0; k0 < K; k0 += 32) {
    __syncthreads();
    gld_lds16(gA + k0,                  lA);
    gld_lds16(gA + k0 + (size_t)64 * K, lA + 64 * 32);
    gld_lds16(gW + k0,                  lB);
    gld_lds16(gW + k0 + (size_t)64 * K, lB + 64 * 32);
    __syncthreads();
    bf16x8 af[4], bfr[4];
#pragma unroll
    for (int i = 0; i < 4; i++) af[i]  = *(const bf16x8*)&As[(wm + i * 16 + l15) * 32 + quad * 8];
#pragma unroll
    for (int j = 0; j < 4; j++) bfr[j] = *(const bf16x8*)&Bs[(wn + j * 16 + l15) * 32 + quad * 8];
#pragma unroll
    for (int i = 0; i < 4; i++)
#pragma unroll
      for (int j = 0; j < 4; j++)
        acc[i][j] = MFMA_BF16(af[i], bfr[j], acc[i][j]);
  }

  if (z == 2) {
#pragma unroll
    for (int i = 0; i < 4; i++) {
      const int mg = m0 + wm + i * 16 + quad * 4;
      const int bb = mg >> 11, ss = mg & 2047;
#pragma unroll
      for (int j = 0; j < 4; j++) {
        const int n = n0 + wn + j * 16 + l15;
        ushort4 pk;
        pk.x = __builtin_bit_cast(unsigned short, (bf16)acc[i][j][0]);
        pk.y = __builtin_bit_cast(unsigned short, (bf16)acc[i][j][1]);
        pk.z = __builtin_bit_cast(unsigned short, (bf16)acc[i][j][2]);
        pk.w = __builtin_bit_cast(unsigned short, (bf16)acc[i][j][3]);
        *(ushort4*)&C[((size_t)bb * 4096 + n) * 2048 + ss] = pk;
      }
    }
  } else {
#pragma unroll
    for (int i = 0; i < 4; i++) {
      const int row = m0 + wm + i * 16 + quad * 4;
#pragma unroll
      for (int j = 0; j < 4; j++) {
        const int col = n0 + wn + j * 16 + l15;
#pragma unroll
        for (int r = 0; r < 4; r++)
          C[(size_t)(row + r) * N + col] = (bf16)acc[i][j][r];
      }
    }
  }
}

// same body, single output, fp32 epilogue
__global__ __launch_bounds__(256) void gemm_out_bf(
    const bf16* __restrict__ A, const bf16* __restrict__ W, float* __restrict__ C)
{
  constexpr int K = 4096, N = 4096;
  __shared__ __align__(16) bf16 As[128 * 32];
  __shared__ __align__(16) bf16 Bs[128 * 32];
  const int tid = threadIdx.x;
  const int lane = tid & 63, wave = tid >> 6;
  const int l15 = lane & 15, quad = lane >> 4;
  const int m0 = blockIdx.x * 128, n0 = blockIdx.y * 128;
  const int wm = (wave & 1) * 64, wn = (wave >> 1) * 64;

  const int srow = tid >> 2;
  const int scol = (tid & 3) * 8;
  const bf16* gA = A + (size_t)(m0 + srow) * K + scol;
  const bf16* gW = W + (size_t)(n0 + srow) * K + scol;
  bf16* lA = &As[srow * 32 + scol];
  bf16* lB = &Bs[srow * 32 + scol];

  f32x4 acc[4][4];
#pragma unroll
  for (int i = 0; i < 4; i++)
#pragma unroll
    for (int j = 0; j < 4; j++) acc[i][j] = (f32x4){0.f, 0.f, 0.f, 0.f};

  for (int k0 = 0; k0 < K; k0 += 32) {
    __syncthreads();
    gld_lds16(gA + k0,                  lA);
    gld_lds16(gA + k0 + (size_t)64 * K, lA + 64 * 32);
    gld_lds16(gW + k0,                  lB);
    gld_lds16(gW + k0 + (size_t)64 * K, lB + 64 * 32);
    __syncthreads();
    bf16x8 af[4], bfr[4];
#pragma unroll
    for (int i = 0; i < 4; i++) af[i]  = *(const bf16x8*)&As[(wm + i * 16 + l15) * 32 + quad * 8];
#pragma unroll
    for (int j = 0; j < 4; j++) bfr[j] = *(const bf16x8*)&Bs[(wn + j * 16 + l15) * 32 + quad * 8];
#pragma unroll
    for (int i = 0; i < 4; i++)
#pragma unroll
      for (int j = 0; j < 4; j++)
        acc[i][j] = MFMA_BF16(af[i], bfr[j], acc[i][j]);
  }

#pragma unroll
  for (int i = 0; i < 4; i++) {
    const int row = m0 + wm + i * 16 + quad * 4;
#pragma unroll
    for (int j = 0; j < 4; j++) {
      const int col = n0 + wn + j * 16 + l15;
#pragma unroll
      for (int r = 0; r < 4; r++)
        C[(size_t)(row + r) * N + col] = acc[i][j][r];
    }
  }
}

// ---------------- fallback QKV GEMM (fp32 inputs, manual staging) ----------------
__global__ __launch_bounds__(256) void gemm_f32in(
    const float* __restrict__ A,
    const float* __restrict__ W0, const float* __restrict__ W1, const float* __restrict__ W2,
    bf16* __restrict__ C0, bf16* __restrict__ C1, bf16* __restrict__ C2)
{
  constexpr int K = 4096, N = 4096;
  __shared__ __align__(16) bf16 As[128 * 32];
  __shared__ __align__(16) bf16 Bs[128 * 32];
  const int z = blockIdx.z;
  const float* __restrict__ W = (z == 0) ? W0 : ((z == 1) ? W1 : W2);
  bf16* __restrict__ C = (z == 0) ? C0 : ((z == 1) ? C1 : C2);
  const int tid = threadIdx.x;
  const int lane = tid & 63, wave = tid >> 6;
  const int l15 = lane & 15, quad = lane >> 4;
  const int m0 = blockIdx.x * 128, n0 = blockIdx.y * 128;
  const int wm = (wave & 1) * 64, wn = (wave >> 1) * 64;

  const int srow = tid >> 2;
  const int scol = (tid & 3) * 8;
  const float* gA = A + (size_t)(m0 + srow) * K + scol;
  const float* gW = W + (size_t)(n0 + srow) * K + scol;
  bf16* lA = &As[srow * 32 + scol];
  bf16* lB = &Bs[srow * 32 + scol];

  f32x4 acc[4][4];
#pragma unroll
  for (int i = 0; i < 4; i++)
#pragma unroll
    for (int j = 0; j < 4; j++) acc[i][j] = (f32x4){0.f, 0.f, 0.f, 0.f};

  for (int k0 = 0; k0 < K; k0 += 32) {
    float4 a0 = *(const float4*)(gA + k0);
    float4 a1 = *(const float4*)(gA + k0 + 4);
    float4 a2 = *(const float4*)(gA + k0 + (size_t)64 * K);
    float4 a3 = *(const float4*)(gA + k0 + (size_t)64 * K + 4);
    float4 b0 = *(const float4*)(gW + k0);
    float4 b1 = *(const float4*)(gW + k0 + 4);
    float4 b2 = *(const float4*)(gW + k0 + (size_t)64 * K);
    float4 b3 = *(const float4*)(gW + k0 + (size_t)64 * K + 4);
    __syncthreads();
    *(bf16x8*)lA              = cvt8(a0, a1);
    *(bf16x8*)(lA + 64 * 32)  = cvt8(a2, a3);
    *(bf16x8*)lB              = cvt8(b0, b1);
    *(bf16x8*)(lB + 64 * 32)  = cvt8(b2, b3);
    __syncthreads();
    bf16x8 af[4], bfr[4];
#pragma unroll
    for (int i = 0; i < 4; i++) af[i]  = *(const bf16x8*)&As[(wm + i * 16 + l15) * 32 + quad * 8];
#pragma unroll
    for (int j = 0; j < 4; j++) bfr[j] = *(const bf16x8*)&Bs[(wn + j * 16 + l15) * 32 + quad * 8];
#pragma unroll
    for (int i = 0; i < 4; i++)
#pragma unroll
      for (int j = 0; j < 4; j++)
        acc[i][j] = MFMA_BF16(af[i], bfr[j], acc[i][j]);
  }

  if (z == 2) {
#pragma unroll
    for (int i = 0; i < 4; i++) {
      const int mg = m0 + wm + i * 16 + quad * 4;
      const int bb = mg >> 11, ss = mg & 2047;
#pragma unroll
      for (int j = 0; j < 4; j++) {
        const int n = n0 + wn + j * 16 + l15;
        ushort4 pk;
        pk.x = __builtin_bit_cast(unsigned short, (bf16)acc[i][j][0]);
        pk.y = __builtin_bit_cast(unsigned short, (bf16)acc[i][j][1]);
        pk.z = __builtin_bit_cast(unsigned short, (bf16)acc[i][j][2]);
        pk.w = __builtin_bit_cast(unsigned short, (bf16)acc[i][j][3]);
        *(ushort4*)&C[((size_t)bb * 4096 + n) * 2048 + ss] = pk;
      }
    }
  } else {
#pragma unroll
    for (int i = 0; i < 4; i++) {
      const int row = m0 + wm + i * 16 + quad * 4;
#pragma unroll
      for (int j = 0; j < 4; j++) {
        const int col = n0 + wn + j * 16 + l15;
#pragma unroll
        for (int r = 0; r < 4; r++)
          C[(size_t)(row + r) * N + col] = (bf16)acc[i][j][r];
      }
    }
  }
}

// Interleaved RoPE on q and k (bf16) in-place; freqs fp32.
__global__ __launch_bounds__(256) void rope_kernel(
    bf16* __restrict__ q, bf16* __restrict__ kk,
    const float* __restrict__ fc, const float* __restrict__ fs)
{
  const int t = blockIdx.x * 256 + threadIdx.x;
  const int i4 = (t & 15) << 2;
  const int row = t >> 4;
  const int s = (row >> 5) & 2047;

  float4 c4 = *(const float4*)(fc + s * 64 + i4);
  float4 s4 = *(const float4*)(fs + s * 64 + i4);
  float c[4]  = {c4.x, c4.y, c4.z, c4.w};
  float sn[4] = {s4.x, s4.y, s4.z, s4.w};

  const int off = row * 128 + (i4 << 1);
  uint4 qv = *(const uint4*)(q + off);
  uint4 kv = *(const uint4*)(kk + off);
  unsigned qa[4] = {qv.x, qv.y, qv.z, qv.w};
  unsigned ka[4] = {kv.x, kv.y, kv.z, kv.w};
#pragma unroll
  for (int p = 0; p < 4; p++) {
    float x0 = __builtin_bit_cast(float, (qa[p] & 0xffffu) << 16);
    float x1 = __builtin_bit_cast(float, (qa[p] >> 16) << 16);
    unsigned lo = __builtin_bit_cast(unsigned short, (bf16)(x0 * c[p] - x1 * sn[p]));
    unsigned hi = __builtin_bit_cast(unsigned short, (bf16)(x0 * sn[p] + x1 * c[p]));
    qa[p] = lo | (hi << 16);
    float y0 = __builtin_bit_cast(float, (ka[p] & 0xffffu) << 16);
    float y1 = __builtin_bit_cast(float, (ka[p] >> 16) << 16);
    lo = __builtin_bit_cast(unsigned short, (bf16)(y0 * c[p] - y1 * sn[p]));
    hi = __builtin_bit_cast(unsigned short, (bf16)(y0 * sn[p] + y1 * c[p]));
    ka[p] = lo | (hi << 16);
  }
  *(uint4*)(q + off)  = make_uint4(qa[0], qa[1], qa[2], qa[3]);
  *(uint4*)(kk + off) = make_uint4(ka[0], ka[1], ka[2], ka[3]);
}

// Flash attention v2: causal, 64 q-rows/block, 128-key chunks.
// LDS: Q 16K | K 32K | V 32K = 80 KB; P (4 waves x 16 x 136) overlaps dead Q + K head.
__global__ __launch_bounds__(256) void flash_attn(
    const bf16* __restrict__ Kg_, const bf16* __restrict__ VT, bf16* __restrict__ QO)
{
  __shared__ __align__(16) char smem[81920];
  bf16* Qs = (bf16*)smem;
  bf16* Ks = (bf16*)(smem + 16384);
  bf16* Vs = (bf16*)(smem + 49152);

  const int tid = threadIdx.x, lane = tid & 63, wave = tid >> 6;
  const int l15 = lane & 15, quad = lane >> 4;
  const int q0 = blockIdx.x * 64, h = blockIdx.y, b = blockIdx.z;

  bf16* Qg       = QO  + ((size_t)(b * 2048 + q0) * 32 + h) * 128;
  const bf16* Kg = Kg_ + ((size_t)b * 2048 * 32 + h) * 128;
  const bf16* Vg = VT  + ((size_t)(b * 32 + h)) * 128 * 2048;

#pragma unroll
  for (int it = 0; it < 4; ++it) {
    int c = it * 256 + tid;
    gld_lds16(Qg + (size_t)(c >> 4) * 4096 + (c & 15) * 8, &Qs[c * 8]);
  }
  __syncthreads();
  bf16x8 qf[4];
#pragma unroll
  for (int ks = 0; ks < 4; ks++)
    qf[ks] = *(const bf16x8*)&Qs[(wave * 16 + l15) * 128 + ks * 32 + quad * 8];

  bf16* Ps = (bf16*)smem + wave * (16 * 136);   // 17408 B total, overlaps Q + K[0:512)

  float m_i[4], l_i[4];
  f32x4 oacc[8];
#pragma unroll
  for (int r = 0; r < 4; r++) { m_i[r] = -INFINITY; l_i[r] = 0.f; }
#pragma unroll
  for (int j = 0; j < 8; j++) oacc[j] = (f32x4){0.f, 0.f, 0.f, 0.f};

  const float SCL = 0.08838834764831845f * 1.4426950408889634f;

  const int nct = (blockIdx.x >> 1) + 1;   // ceil((q0+64)/128)
  for (int ct = 0; ct < nct; ++ct) {
    __syncthreads();   // prev PV reads done; safe to restage K/V (and clobber P residue)
    const bf16* Kt = Kg + (size_t)ct * 128 * 4096;
    const bf16* Vt = Vg + ct * 128;
#pragma unroll
    for (int it = 0; it < 8; ++it) {
      int c = it * 256 + tid;   // 0..2047
      gld_lds16(Kt + (size_t)(c >> 4) * 4096 + (c & 15) * 8, &Ks[c * 8]);
      gld_lds16(Vt + (size_t)(c >> 4) * 2048 + (c & 15) * 8, &Vs[c * 8]);
    }
    __syncthreads();

    f32x4 sacc[8];
#pragma unroll
    for (int nb = 0; nb < 8; nb++) {
      f32x4 a = (f32x4){0.f, 0.f, 0.f, 0.f};
#pragma unroll
      for (int ks = 0; ks < 4; ks++) {
        bf16x8 kf = *(const bf16x8*)&Ks[(nb * 16 + l15) * 128 + ks * 32 + quad * 8];
        a = MFMA_BF16(qf[ks], kf, a);
      }
      sacc[nb] = a;
    }

    const int qb = q0 + wave * 16 + quad * 4;
    const int kbase = ct * 128 + l15;
    float alpha[4];
#pragma unroll
    for (int r = 0; r < 4; r++) {
      float mx = -INFINITY;
#pragma unroll
      for (int nb = 0; nb < 8; nb++) {
        float s = sacc[nb][r] * SCL;
        if (kbase + nb * 16 > qb + r) s = -INFINITY;
        sacc[nb][r] = s;
        mx = fmaxf(mx, s);
      }
#pragma unroll
      for (int off = 1; off < 16; off <<= 1) mx = fmaxf(mx, __shfl_xor(mx, off));
      float mn = fmaxf(m_i[r], mx);
      alpha[r] = exp2f(m_i[r] - mn);
      m_i[r] = mn;
      float rs = 0.f;
#pragma unroll
      for (int nb = 0; nb < 8; nb++) {
        float p = exp2f(sacc[nb][r] - mn);
        rs += p;
        Ps[(quad * 4 + r) * 136 + nb * 16 + l15] = (bf16)p;
      }
#pragma unroll
      for (int off = 1; off < 16; off <<= 1) rs += __shfl_xor(rs, off);
      l_i[r] = l_i[r] * alpha[r] + rs;
    }
#pragma unroll
    for (int j = 0; j < 8; j++)
#pragma unroll
      for (int r = 0; r < 4; r++) oacc[j][r] *= alpha[r];

    __syncthreads();   // P visible

#pragma unroll
    for (int ks2 = 0; ks2 < 4; ks2++) {
      bf16x8 pf = *(const bf16x8*)&Ps[l15 * 136 + ks2 * 32 + quad * 8];
#pragma unroll
      for (int j = 0; j < 8; j++) {
        bf16x8 vf = *(const bf16x8*)&Vs[(j * 16 + l15) * 128 + ks2 * 32 + quad * 8];
        oacc[j] = MFMA_BF16(pf, vf, oacc[j]);
      }
    }
  }

#pragma unroll
  for (int r = 0; r < 4; r++) {
    const float inv = 1.f / l_i[r];
    const int row = q0 + wave * 16 + quad * 4 + r;
    bf16* Og = QO + ((size_t)(b * 2048 + row) * 32 + h) * 128;
#pragma unroll
    for (int j = 0; j < 8; j++) Og[j * 16 + l15] = (bf16)(oacc[j][r] * inv);
  }
}

extern "C" void kernel_launch(void* const* d_in, const int* in_sizes, int n_in,
                              void* d_out, int out_size, void* d_ws, size_t ws_size,
                              hipStream_t stream) {
  const float* x  = (const float*)d_in[0];
  const float* wq = (const float*)d_in[1];
  const float* wk = (const float*)d_in[2];
  const float* wv = (const float*)d_in[3];
  const float* wo = (const float*)d_in[4];
  const float* fc = (const float*)d_in[5];
  const float* fs = (const float*)d_in[6];
  float* out = (float*)d_out;

  float sentinel = 0.f;
  if (n_in < 9 || in_sizes[0] != 16777216) sentinel = 200.f;
  else if (out_size != 16777216)           sentinel = 300.f;
  else if (in_sizes[5] != 131072)          sentinel = 400.f;
  else if (ws_size < 3ull * 33554432ull)   sentinel = 100.f;
  if (sentinel != 0.f) {
    fill_kernel<<<dim3((out_size + 255) / 256), dim3(256), 0, stream>>>(out, out_size, sentinel);
    return;
  }

  bf16* q  = (bf16*)d_ws;                    // becomes attention output in-place
  bf16* k  = q  + (size_t)16777216;          // later reused for bf16(wo)
  bf16* vt = k  + (size_t)16777216;

  dim3 blk(256, 1, 1);
  const bool bigws = (ws_size >= 7ull * 33554432ull);   // 224 MiB

  if (bigws) {
    bf16* xb  = vt  + (size_t)16777216;
    bf16* wqb = xb  + (size_t)16777216;
    bf16* wkb = wqb + (size_t)16777216;
    bf16* wvb = wkb + (size_t)16777216;
    cvt_kernel<<<dim3(16384), blk, 0, stream>>>(x,  xb);
    cvt_kernel<<<dim3(16384), blk, 0, stream>>>(wq, wqb);
    cvt_kernel<<<dim3(16384), blk, 0, stream>>>(wk, wkb);
    cvt_kernel<<<dim3(16384), blk, 0, stream>>>(wv, wvb);
    gemm_bt_bf<<<dim3(32, 32, 3), blk, 0, stream>>>(xb, wqb, wkb, wvb, q, k, vt);
  } else {
    gemm_f32in<<<dim3(32, 32, 3), blk, 0, stream>>>(x, wq, wk, wv, q, k, vt);
  }
  rope_kernel<<<dim3(8192), blk, 0, stream>>>(q, k, fc, fs);
  flash_attn<<<dim3(32, 32, 2), blk, 0, stream>>>(k, vt, q);
  cvt_kernel<<<dim3(16384), blk, 0, stream>>>(wo, k);          // k buffer now dead -> bf16(wo)
  gemm_out_bf<<<dim3(32, 32, 1), blk, 0, stream>>>(q, k, out);
}